// Round 12
// baseline (87.788 us; speedup 1.0000x reference)
//
#include <hip/hip_runtime.h>
#include <hip/hip_bf16.h>

// out[e] = relu(concat(emb[src], emb[dst]) @ w1 + b1) @ w2
// Restructure: P[n][j]    = emb[n] . w1[0:128, j]  + b1[j]   (j < 64)
//              P[n][64+j] = emb[n] . w1[128:256, j]          (j < 64)
// out[e] = sum_j relu(P[src][j] + P[dst][64+j]) * w2[j]
// P via bf16 MFMA (16x16x32, swapped operands -> lane holds 4 consecutive
// P-cols of one node), stored bf16. absmax ~0.03 vs threshold 0.126.
//
// R12 = R9 structure (B-fragments hoisted to regs — VGPR_Count measured 128,
// NOT a squeeze) with DOUBLE residency: grid 1024, launch_bounds(256,4)
// -> 4 blocks/CU x 4 waves = 16 waves/CU (VGPR cap 2048/16 = 128 = fits
// exactly; LDS 32KB x 4 = 128KB). R10 proved steady-state is TLP-starved
// (3.9 TB/s at 8 waves/CU); R9's 512-block grid was self-imposed.

#define D_FEAT 128
#define HIDDEN 64

typedef __attribute__((ext_vector_type(8))) short v8s;      // 8 bf16 (4 VGPRs)
typedef __attribute__((ext_vector_type(4))) float f32x4;    // 4 f32
typedef __attribute__((ext_vector_type(4))) unsigned u32x4; // 4 u32

// round-to-nearest (ties away): bits + 0x8000, take high 16. 2 VALU ops.
__device__ inline unsigned short f2bf_rn(float f) {
    unsigned u = __builtin_bit_cast(unsigned, f) + 0x8000u;
    return (unsigned short)(u >> 16);
}
// pack two f32 -> one u32 of 2 bf16 (lo in low half): 2 adds + 1 v_perm_b32.
__device__ inline unsigned pack2(float lo, float hi) {
    unsigned ul = __builtin_bit_cast(unsigned, lo) + 0x8000u;
    unsigned uh = __builtin_bit_cast(unsigned, hi) + 0x8000u;
    return __builtin_amdgcn_perm(uh, ul, 0x07060302u);  // {uh[31:16],ul[31:16]}
}

// int64-vs-int32 detection: int64 (LE, idx < 2^31) => every odd int32 word 0.
__device__ inline bool detect_is64(const int* ts32, int lane) {
    int probe = ts32[2 * lane + 1];
    return __ballot(probe != 0) == 0ULL;
}

// ---------------------------------------------------------------------------
// Persistent precompute of P (n_nodes x 128, bf16). 1024 blocks x 4 waves;
// Bt built once per block, B-fragments hoisted to regs, depth-1 A prefetch.
__global__ void __launch_bounds__(256, 4)
precompute_kernel(const float* __restrict__ emb, const float* __restrict__ w1,
                  const float* __restrict__ b1, unsigned short* __restrict__ P,
                  int n_nodes) {
    __shared__ unsigned short bt[16384];   // Bt[c][k] at (c*128+k)^((c&7)<<3)
    const int t    = threadIdx.x;
    const int lane = t & 63;
    const int wid  = t >> 6;
    const int sub  = lane & 15;   // node within tile / D col
    const int g    = lane >> 4;   // k-group / D row group

    // ---- build swizzled Bt from w1 (256x64 f32): thread t owns w1 row t.
    {
        const int k    = t & 127;
        const int half = t >> 7;
        const float4* src = reinterpret_cast<const float4*>(w1 + (size_t)t * 64);
#pragma unroll
        for (int j4 = 0; j4 < 16; ++j4) {
            const float4 v = src[j4];
            const int cb = half * 64 + j4 * 4;
            bt[((cb + 0) * 128 + k) ^ (((cb + 0) & 7) << 3)] = f2bf_rn(v.x);
            bt[((cb + 1) * 128 + k) ^ (((cb + 1) & 7) << 3)] = f2bf_rn(v.y);
            bt[((cb + 2) * 128 + k) ^ (((cb + 2) & 7) << 3)] = f2bf_rn(v.z);
            bt[((cb + 3) * 128 + k) ^ (((cb + 3) & 7) << 3)] = f2bf_rn(v.w);
        }
    }

    // bias regs (cols < 64 only, i.e. nj < 4): cols nj*16 + g*4 .. +3
    float4 bias[4];
#pragma unroll
    for (int nj = 0; nj < 4; ++nj)
        bias[nj] = *reinterpret_cast<const float4*>(b1 + nj * 16 + g * 4);

    __syncthreads();   // Bt ready

    // ---- hoist ALL B-fragments to registers (tile-invariant): 32 x v8s.
    // Measured (R10): total VGPR_Count = 128 with this hoist (acc -> AGPRs).
    v8s B[4][8];
#pragma unroll
    for (int ks = 0; ks < 4; ++ks)
#pragma unroll
        for (int nj = 0; nj < 8; ++nj) {
            const int c = nj * 16 + sub;
            const int eidx = (c * 128 + ks * 32 + g * 8) ^ ((c & 7) << 3);
            B[ks][nj] = *reinterpret_cast<const v8s*>(&bt[eidx]);
        }

    const int ntiles = (n_nodes + 15) / 16;
    const int gwave  = blockIdx.x * 4 + wid;
    const int nwave  = gridDim.x * 4;

    auto loadA = [&](float4* a, int tt) {
        int row = tt * 16 + sub;
        if (row >= n_nodes) row = n_nodes - 1;
        const float* p = emb + (size_t)row * D_FEAT + g * 8;
#pragma unroll
        for (int ks = 0; ks < 4; ++ks) {
            a[2 * ks]     = *reinterpret_cast<const float4*>(p + ks * 32);
            a[2 * ks + 1] = *reinterpret_cast<const float4*>(p + ks * 32 + 4);
        }
    };

    float4 A0[8], A1[8];
    if (gwave < ntiles) loadA(A0, gwave);

    for (int tt = gwave; tt < ntiles; tt += nwave) {
        const int tn = tt + nwave;
        if (tn < ntiles) loadA(A1, tn);   // prefetch next tile

        f32x4 acc[8];
#pragma unroll
        for (int nj = 0; nj < 8; ++nj) acc[nj] = (f32x4){0.f, 0.f, 0.f, 0.f};

#pragma unroll
        for (int ks = 0; ks < 4; ++ks) {
            const float4 a0 = A0[2 * ks], a1 = A0[2 * ks + 1];
            u32x4 ap;
            ap[0] = pack2(a0.x, a0.y);
            ap[1] = pack2(a0.z, a0.w);
            ap[2] = pack2(a1.x, a1.y);
            ap[3] = pack2(a1.z, a1.w);
            const v8s af = __builtin_bit_cast(v8s, ap);
#pragma unroll
            for (int nj = 0; nj < 8; ++nj)
                // swapped: D[c][node], col=node=sub, row=c_local=g*4+reg
                acc[nj] = __builtin_amdgcn_mfma_f32_16x16x32_bf16(B[ks][nj], af,
                                                                  acc[nj], 0, 0, 0);
        }

        // epilogue: lane holds P cols nj*16+g*4..+3 for node tt*16+sub
        const int node = tt * 16 + sub;
        if (node < n_nodes) {
            unsigned short* prow = P + (size_t)node * 128;
#pragma unroll
            for (int nj = 0; nj < 8; ++nj) {
                float s0 = acc[nj][0], s1 = acc[nj][1];
                float s2 = acc[nj][2], s3 = acc[nj][3];
                if (nj < 4) { s0 += bias[nj].x; s1 += bias[nj].y;
                              s2 += bias[nj].z; s3 += bias[nj].w; }
                uint2 o;
                o.x = pack2(s0, s1);
                o.y = pack2(s2, s3);
                *reinterpret_cast<uint2*>(prow + nj * 16 + g * 4) = o;
            }
        }

#pragma unroll
        for (int i = 0; i < 8; ++i) A0[i] = A1[i];
    }
}

// ---------------------------------------------------------------------------
// Edge pass: 8 lanes per edge, 8 edges per wave. 16B uint4 loads per half,
// bf16 unpack via bit ops, 3-step shuffle reduce. (measured ~9.3 us warm)
__device__ inline float pairterm(unsigned aw, unsigned bw, float w0, float w1) {
    float a0 = __builtin_bit_cast(float, aw << 16);
    float a1 = __builtin_bit_cast(float, aw & 0xFFFF0000u);
    float b0 = __builtin_bit_cast(float, bw << 16);
    float b1 = __builtin_bit_cast(float, bw & 0xFFFF0000u);
    float h0 = a0 + b0; h0 = h0 > 0.f ? h0 : 0.f;
    float h1 = a1 + b1; h1 = h1 > 0.f ? h1 : 0.f;
    return h0 * w0 + h1 * w1;
}

__global__ void __launch_bounds__(256)
edge_kernel(const unsigned short* __restrict__ P, const void* __restrict__ ts,
            const float* __restrict__ w2, float* __restrict__ out, int n_edges) {
    const int lane = threadIdx.x & 63;
    const int wid  = threadIdx.x >> 6;
    const int sub  = lane & 7;   // 8 lanes per edge
    const int grp  = lane >> 3;  // 8 edges per wave
    const int gw   = blockIdx.x * 4 + wid;
    const int nw   = gridDim.x * 4;

    const int* ts32 = (const int*)ts;
    const long long* ts64 = (const long long*)ts;
    const bool is64 = detect_is64(ts32, lane);

    const float4 w2a = *reinterpret_cast<const float4*>(w2 + sub * 8);
    const float4 w2b = *reinterpret_cast<const float4*>(w2 + sub * 8 + 4);

    for (int e = gw * 8 + grp; e < n_edges; e += nw * 8) {
        long long s, d;
        if (is64) { s = ts64[2 * e]; d = ts64[2 * e + 1]; }
        else      { s = ts32[2 * e]; d = ts32[2 * e + 1]; }
        const uint4 a = *reinterpret_cast<const uint4*>(P + (size_t)s * 128 + sub * 8);
        const uint4 b = *reinterpret_cast<const uint4*>(P + (size_t)d * 128 + 64 + sub * 8);
        float v = pairterm(a.x, b.x, w2a.x, w2a.y)
                + pairterm(a.y, b.y, w2a.z, w2a.w)
                + pairterm(a.z, b.z, w2b.x, w2b.y)
                + pairterm(a.w, b.w, w2b.z, w2b.w);
#pragma unroll
        for (int off = 1; off < 8; off <<= 1) v += __shfl_xor(v, off);
        if (sub == 0) out[e] = v;
    }
}

// ---------------------------------------------------------------------------
// Fallback (ws too small for P): fused gather + f32 MLP, wave per edge.
__global__ void __launch_bounds__(256)
direct_kernel(const float* __restrict__ emb, const void* __restrict__ ts,
              const float* __restrict__ w1, const float* __restrict__ b1,
              const float* __restrict__ w2, float* __restrict__ out, int n_edges) {
    const int lane = threadIdx.x & 63;
    const int gw   = blockIdx.x * (blockDim.x >> 6) + (threadIdx.x >> 6);
    const int nw   = gridDim.x * (blockDim.x >> 6);
    const float w2v  = w2[lane];
    const float bias = b1[lane];
    const int* ts32 = (const int*)ts;
    const long long* ts64 = (const long long*)ts;
    const bool is64 = detect_is64(ts32, lane);

    for (int e = gw; e < n_edges; e += nw) {
        long long s, d;
        if (is64) { s = ts64[2 * e]; d = ts64[2 * e + 1]; }
        else      { s = ts32[2 * e]; d = ts32[2 * e + 1]; }
        const float4* s4 = reinterpret_cast<const float4*>(emb + s * D_FEAT);
        const float4* d4 = reinterpret_cast<const float4*>(emb + d * D_FEAT);
        float acc = bias;
#pragma unroll
        for (int k4 = 0; k4 < 32; ++k4) {
            float4 r = s4[k4];
            acc += r.x * w1[(4 * k4 + 0) * 64 + lane];
            acc += r.y * w1[(4 * k4 + 1) * 64 + lane];
            acc += r.z * w1[(4 * k4 + 2) * 64 + lane];
            acc += r.w * w1[(4 * k4 + 3) * 64 + lane];
        }
#pragma unroll
        for (int k4 = 0; k4 < 32; ++k4) {
            float4 r = d4[k4];
            acc += r.x * w1[(128 + 4 * k4 + 0) * 64 + lane];
            acc += r.y * w1[(128 + 4 * k4 + 1) * 64 + lane];
            acc += r.z * w1[(128 + 4 * k4 + 2) * 64 + lane];
            acc += r.w * w1[(128 + 4 * k4 + 3) * 64 + lane];
        }
        float h = acc > 0.0f ? acc : 0.0f;
        float v = h * w2v;
#pragma unroll
        for (int off = 32; off > 0; off >>= 1) v += __shfl_xor(v, off);
        if (lane == 0) out[e] = v;
    }
}

// ---------------------------------------------------------------------------
extern "C" void kernel_launch(void* const* d_in, const int* in_sizes, int n_in,
                              void* d_out, int out_size, void* d_ws, size_t ws_size,
                              hipStream_t stream) {
    const float* emb = (const float*)d_in[0];
    const void*  ts  = d_in[1];
    const float* w1  = (const float*)d_in[2];
    const float* b1  = (const float*)d_in[3];
    const float* w2  = (const float*)d_in[4];
    float* out = (float*)d_out;

    const int n_nodes = in_sizes[0] / D_FEAT;   // 100000
    const int n_edges = in_sizes[1] / 2;        // 300000

    const size_t p_bytes = (size_t)n_nodes * 128 * sizeof(unsigned short);

    if (ws_size >= p_bytes) {
        unsigned short* P = (unsigned short*)d_ws;
        // 1024 blocks = 4 blocks/CU x 4 waves = 16 waves/CU (VGPR-128 cap);
        // 6250 tiles -> ~1.5 tiles/wave.
        precompute_kernel<<<1024, 256, 0, stream>>>(emb, w1, b1, P, n_nodes);
        edge_kernel<<<2048, 256, 0, stream>>>(P, ts, w2, out, n_edges);
    } else {
        direct_kernel<<<2048, 256, 0, stream>>>(emb, ts, w1, b1, w2, out, n_edges);
    }
}

// Round 13
// 41.344 us; speedup vs baseline: 2.1233x; 2.1233x over previous
//
#include <hip/hip_runtime.h>
#include <hip/hip_bf16.h>

// out[e] = relu(concat(emb[src], emb[dst]) @ w1 + b1) @ w2
// Restructure: P[n][j]    = emb[n] . w1[0:128, j]  + b1[j]   (j < 64)
//              P[n][64+j] = emb[n] . w1[128:256, j]          (j < 64)
// out[e] = sum_j relu(P[src][j] + P[dst][64+j]) * w2[j]
// P via bf16 MFMA (16x16x32, swapped operands), stored bf16. absmax ~0.03.
//
// R13 = R9 kernel (B-hoist, measured VGPR=128 no-spill under lb(256,2))
// with grid 1024 (4 blocks/CU resident at VGPR-128's 16-wave cap; LDS 128KB).
// R12's mistake was lb(256,4): a 64-VGPR *cap* -> full B-spill (FETCH 117MB,
// WRITE 145MB). lb(256,2) is a minimum — HW residency comes from VGPR=128.
// Micro-fix: A0/A1 loads issued at kernel entry, before the Bt build, so
// first-tile latency hides under the LDS build (matters at 1.5 tiles/wave).

#define D_FEAT 128
#define HIDDEN 64

typedef __attribute__((ext_vector_type(8))) short v8s;      // 8 bf16 (4 VGPRs)
typedef __attribute__((ext_vector_type(4))) float f32x4;    // 4 f32
typedef __attribute__((ext_vector_type(4))) unsigned u32x4; // 4 u32

// round-to-nearest (ties away): bits + 0x8000, take high 16. 2 VALU ops.
__device__ inline unsigned short f2bf_rn(float f) {
    unsigned u = __builtin_bit_cast(unsigned, f) + 0x8000u;
    return (unsigned short)(u >> 16);
}
// pack two f32 -> one u32 of 2 bf16 (lo in low half): 2 adds + 1 v_perm_b32.
__device__ inline unsigned pack2(float lo, float hi) {
    unsigned ul = __builtin_bit_cast(unsigned, lo) + 0x8000u;
    unsigned uh = __builtin_bit_cast(unsigned, hi) + 0x8000u;
    return __builtin_amdgcn_perm(uh, ul, 0x07060302u);  // {uh[31:16],ul[31:16]}
}

// int64-vs-int32 detection: int64 (LE, idx < 2^31) => every odd int32 word 0.
__device__ inline bool detect_is64(const int* ts32, int lane) {
    int probe = ts32[2 * lane + 1];
    return __ballot(probe != 0) == 0ULL;
}

// ---------------------------------------------------------------------------
// Persistent precompute of P (n_nodes x 128, bf16). 1024 blocks x 4 waves.
__global__ void __launch_bounds__(256, 2)
precompute_kernel(const float* __restrict__ emb, const float* __restrict__ w1,
                  const float* __restrict__ b1, unsigned short* __restrict__ P,
                  int n_nodes) {
    __shared__ unsigned short bt[16384];   // Bt[c][k] at (c*128+k)^((c&7)<<3)
    const int t    = threadIdx.x;
    const int lane = t & 63;
    const int wid  = t >> 6;
    const int sub  = lane & 15;   // node within tile / D col
    const int g    = lane >> 4;   // k-group / D row group

    const int ntiles = (n_nodes + 15) / 16;
    const int gwave  = blockIdx.x * 4 + wid;
    const int nwave  = gridDim.x * 4;

    auto loadA = [&](float4* a, int tt) {
        int row = tt * 16 + sub;
        if (row >= n_nodes) row = n_nodes - 1;
        const float* p = emb + (size_t)row * D_FEAT + g * 8;
#pragma unroll
        for (int ks = 0; ks < 4; ++ks) {
            a[2 * ks]     = *reinterpret_cast<const float4*>(p + ks * 32);
            a[2 * ks + 1] = *reinterpret_cast<const float4*>(p + ks * 32 + 4);
        }
    };

    // ---- issue tile-0 and tile-1 A-loads FIRST: latency overlaps Bt build
    float4 A0[8], A1[8];
    if (gwave < ntiles)          loadA(A0, gwave);
    if (gwave + nwave < ntiles)  loadA(A1, gwave + nwave);

    // ---- build swizzled Bt from w1 (256x64 f32): thread t owns w1 row t.
    {
        const int k    = t & 127;
        const int half = t >> 7;
        const float4* src = reinterpret_cast<const float4*>(w1 + (size_t)t * 64);
#pragma unroll
        for (int j4 = 0; j4 < 16; ++j4) {
            const float4 v = src[j4];
            const int cb = half * 64 + j4 * 4;
            bt[((cb + 0) * 128 + k) ^ (((cb + 0) & 7) << 3)] = f2bf_rn(v.x);
            bt[((cb + 1) * 128 + k) ^ (((cb + 1) & 7) << 3)] = f2bf_rn(v.y);
            bt[((cb + 2) * 128 + k) ^ (((cb + 2) & 7) << 3)] = f2bf_rn(v.z);
            bt[((cb + 3) * 128 + k) ^ (((cb + 3) & 7) << 3)] = f2bf_rn(v.w);
        }
    }

    // bias regs (cols < 64 only, i.e. nj < 4): cols nj*16 + g*4 .. +3
    float4 bias[4];
#pragma unroll
    for (int nj = 0; nj < 4; ++nj)
        bias[nj] = *reinterpret_cast<const float4*>(b1 + nj * 16 + g * 4);

    __syncthreads();   // Bt ready

    // ---- hoist ALL B-fragments to registers (tile-invariant): 32 x v8s.
    v8s B[4][8];
#pragma unroll
    for (int ks = 0; ks < 4; ++ks)
#pragma unroll
        for (int nj = 0; nj < 8; ++nj) {
            const int c = nj * 16 + sub;
            const int eidx = (c * 128 + ks * 32 + g * 8) ^ ((c & 7) << 3);
            B[ks][nj] = *reinterpret_cast<const v8s*>(&bt[eidx]);
        }

    for (int tt = gwave; tt < ntiles; tt += nwave) {
        const int tn2 = tt + 2 * nwave;
        // A1 holds next tile (loaded at entry or previous rotate); prefetch
        // the one after into A1 after consuming the rotate below.
        f32x4 acc[8];
#pragma unroll
        for (int nj = 0; nj < 8; ++nj) acc[nj] = (f32x4){0.f, 0.f, 0.f, 0.f};

#pragma unroll
        for (int ks = 0; ks < 4; ++ks) {
            const float4 a0 = A0[2 * ks], a1 = A0[2 * ks + 1];
            u32x4 ap;
            ap[0] = pack2(a0.x, a0.y);
            ap[1] = pack2(a0.z, a0.w);
            ap[2] = pack2(a1.x, a1.y);
            ap[3] = pack2(a1.z, a1.w);
            const v8s af = __builtin_bit_cast(v8s, ap);
#pragma unroll
            for (int nj = 0; nj < 8; ++nj)
                // swapped: D[c][node], col=node=sub, row=c_local=g*4+reg
                acc[nj] = __builtin_amdgcn_mfma_f32_16x16x32_bf16(B[ks][nj], af,
                                                                  acc[nj], 0, 0, 0);
        }

        // rotate: A0 <- A1, then prefetch tile tt+2*nwave into A1 while the
        // epilogue stores run.
#pragma unroll
        for (int i = 0; i < 8; ++i) A0[i] = A1[i];
        if (tn2 < ntiles) loadA(A1, tn2);

        // epilogue: lane holds P cols nj*16+g*4..+3 for node tt*16+sub
        const int node = tt * 16 + sub;
        if (node < n_nodes) {
            unsigned short* prow = P + (size_t)node * 128;
#pragma unroll
            for (int nj = 0; nj < 8; ++nj) {
                float s0 = acc[nj][0], s1 = acc[nj][1];
                float s2 = acc[nj][2], s3 = acc[nj][3];
                if (nj < 4) { s0 += bias[nj].x; s1 += bias[nj].y;
                              s2 += bias[nj].z; s3 += bias[nj].w; }
                uint2 o;
                o.x = pack2(s0, s1);
                o.y = pack2(s2, s3);
                *reinterpret_cast<uint2*>(prow + nj * 16 + g * 4) = o;
            }
        }
    }
}

// ---------------------------------------------------------------------------
// Edge pass: 8 lanes per edge, 8 edges per wave. 16B uint4 loads per half,
// bf16 unpack via bit ops, 3-step shuffle reduce. (measured ~9.3 us warm)
__device__ inline float pairterm(unsigned aw, unsigned bw, float w0, float w1) {
    float a0 = __builtin_bit_cast(float, aw << 16);
    float a1 = __builtin_bit_cast(float, aw & 0xFFFF0000u);
    float b0 = __builtin_bit_cast(float, bw << 16);
    float b1 = __builtin_bit_cast(float, bw & 0xFFFF0000u);
    float h0 = a0 + b0; h0 = h0 > 0.f ? h0 : 0.f;
    float h1 = a1 + b1; h1 = h1 > 0.f ? h1 : 0.f;
    return h0 * w0 + h1 * w1;
}

__global__ void __launch_bounds__(256)
edge_kernel(const unsigned short* __restrict__ P, const void* __restrict__ ts,
            const float* __restrict__ w2, float* __restrict__ out, int n_edges) {
    const int lane = threadIdx.x & 63;
    const int wid  = threadIdx.x >> 6;
    const int sub  = lane & 7;   // 8 lanes per edge
    const int grp  = lane >> 3;  // 8 edges per wave
    const int gw   = blockIdx.x * 4 + wid;
    const int nw   = gridDim.x * 4;

    const int* ts32 = (const int*)ts;
    const long long* ts64 = (const long long*)ts;
    const bool is64 = detect_is64(ts32, lane);

    const float4 w2a = *reinterpret_cast<const float4*>(w2 + sub * 8);
    const float4 w2b = *reinterpret_cast<const float4*>(w2 + sub * 8 + 4);

    for (int e = gw * 8 + grp; e < n_edges; e += nw * 8) {
        long long s, d;
        if (is64) { s = ts64[2 * e]; d = ts64[2 * e + 1]; }
        else      { s = ts32[2 * e]; d = ts32[2 * e + 1]; }
        const uint4 a = *reinterpret_cast<const uint4*>(P + (size_t)s * 128 + sub * 8);
        const uint4 b = *reinterpret_cast<const uint4*>(P + (size_t)d * 128 + 64 + sub * 8);
        float v = pairterm(a.x, b.x, w2a.x, w2a.y)
                + pairterm(a.y, b.y, w2a.z, w2a.w)
                + pairterm(a.z, b.z, w2b.x, w2b.y)
                + pairterm(a.w, b.w, w2b.z, w2b.w);
#pragma unroll
        for (int off = 1; off < 8; off <<= 1) v += __shfl_xor(v, off);
        if (sub == 0) out[e] = v;
    }
}

// ---------------------------------------------------------------------------
// Fallback (ws too small for P): fused gather + f32 MLP, wave per edge.
__global__ void __launch_bounds__(256)
direct_kernel(const float* __restrict__ emb, const void* __restrict__ ts,
              const float* __restrict__ w1, const float* __restrict__ b1,
              const float* __restrict__ w2, float* __restrict__ out, int n_edges) {
    const int lane = threadIdx.x & 63;
    const int gw   = blockIdx.x * (blockDim.x >> 6) + (threadIdx.x >> 6);
    const int nw   = gridDim.x * (blockDim.x >> 6);
    const float w2v  = w2[lane];
    const float bias = b1[lane];
    const int* ts32 = (const int*)ts;
    const long long* ts64 = (const long long*)ts;
    const bool is64 = detect_is64(ts32, lane);

    for (int e = gw; e < n_edges; e += nw) {
        long long s, d;
        if (is64) { s = ts64[2 * e]; d = ts64[2 * e + 1]; }
        else      { s = ts32[2 * e]; d = ts32[2 * e + 1]; }
        const float4* s4 = reinterpret_cast<const float4*>(emb + s * D_FEAT);
        const float4* d4 = reinterpret_cast<const float4*>(emb + d * D_FEAT);
        float acc = bias;
#pragma unroll
        for (int k4 = 0; k4 < 32; ++k4) {
            float4 r = s4[k4];
            acc += r.x * w1[(4 * k4 + 0) * 64 + lane];
            acc += r.y * w1[(4 * k4 + 1) * 64 + lane];
            acc += r.z * w1[(4 * k4 + 2) * 64 + lane];
            acc += r.w * w1[(4 * k4 + 3) * 64 + lane];
        }
#pragma unroll
        for (int k4 = 0; k4 < 32; ++k4) {
            float4 r = d4[k4];
            acc += r.x * w1[(128 + 4 * k4 + 0) * 64 + lane];
            acc += r.y * w1[(128 + 4 * k4 + 1) * 64 + lane];
            acc += r.z * w1[(128 + 4 * k4 + 2) * 64 + lane];
            acc += r.w * w1[(128 + 4 * k4 + 3) * 64 + lane];
        }
        float h = acc > 0.0f ? acc : 0.0f;
        float v = h * w2v;
#pragma unroll
        for (int off = 32; off > 0; off >>= 1) v += __shfl_xor(v, off);
        if (lane == 0) out[e] = v;
    }
}

// ---------------------------------------------------------------------------
extern "C" void kernel_launch(void* const* d_in, const int* in_sizes, int n_in,
                              void* d_out, int out_size, void* d_ws, size_t ws_size,
                              hipStream_t stream) {
    const float* emb = (const float*)d_in[0];
    const void*  ts  = d_in[1];
    const float* w1  = (const float*)d_in[2];
    const float* b1  = (const float*)d_in[3];
    const float* w2  = (const float*)d_in[4];
    float* out = (float*)d_out;

    const int n_nodes = in_sizes[0] / D_FEAT;   // 100000
    const int n_edges = in_sizes[1] / 2;        // 300000

    const size_t p_bytes = (size_t)n_nodes * 128 * sizeof(unsigned short);

    if (ws_size >= p_bytes) {
        unsigned short* P = (unsigned short*)d_ws;
        // 1024 blocks; residency 4 blocks/CU via VGPR=128 (16-wave cap),
        // NOT via launch_bounds (which stays (256,2) = 256-VGPR budget).
        precompute_kernel<<<1024, 256, 0, stream>>>(emb, w1, b1, P, n_nodes);
        edge_kernel<<<2048, 256, 0, stream>>>(P, ts, w2, out, n_edges);
    } else {
        direct_kernel<<<2048, 256, 0, stream>>>(emb, ts, w1, b1, w2, out, n_edges);
    }
}

// Round 14
// 37.448 us; speedup vs baseline: 2.3443x; 1.1040x over previous
//
#include <hip/hip_runtime.h>
#include <hip/hip_bf16.h>

// out[e] = relu(concat(emb[src], emb[dst]) @ w1 + b1) @ w2
// Restructure: P[n][j]    = emb[n] . w1[0:128, j]  + b1[j]   (j < 64)
//              P[n][64+j] = emb[n] . w1[128:256, j]          (j < 64)
// out[e] = sum_j relu(P[src][j] + P[dst][64+j]) * w2[j]
// P via bf16 MFMA (16x16x32, swapped operands -> lane holds 4 consecutive
// P-cols of one node), stored bf16. absmax ~0.03 vs threshold 0.126.
//
// R14 = exact revert to R9 (best measured: 37.5 us). Tried and rejected:
//   R11 depth-2 prefetch + B-from-LDS (43.3), R12 lb(256,4) spill (87.8),
//   R13 1024-block grid (41.3). 512 blocks / B-hoist / depth-1 is the basin
//   optimum. Floor: 77MB compulsory HBM (L3 flushed per replay) ~12.7us +
//   ~11us cold-latency exposure (R10 ablation) + edge 9.3us (R6 ablation)
//   + ~4us launch = ~37.5us.

#define D_FEAT 128
#define HIDDEN 64

typedef __attribute__((ext_vector_type(8))) short v8s;      // 8 bf16 (4 VGPRs)
typedef __attribute__((ext_vector_type(4))) float f32x4;    // 4 f32
typedef __attribute__((ext_vector_type(4))) unsigned u32x4; // 4 u32

// round-to-nearest (ties away): bits + 0x8000, take high 16. 2 VALU ops.
__device__ inline unsigned short f2bf_rn(float f) {
    unsigned u = __builtin_bit_cast(unsigned, f) + 0x8000u;
    return (unsigned short)(u >> 16);
}
// pack two f32 -> one u32 of 2 bf16 (lo in low half): 2 adds + 1 v_perm_b32.
__device__ inline unsigned pack2(float lo, float hi) {
    unsigned ul = __builtin_bit_cast(unsigned, lo) + 0x8000u;
    unsigned uh = __builtin_bit_cast(unsigned, hi) + 0x8000u;
    return __builtin_amdgcn_perm(uh, ul, 0x07060302u);  // {uh[31:16],ul[31:16]}
}

// int64-vs-int32 detection: int64 (LE, idx < 2^31) => every odd int32 word 0.
__device__ inline bool detect_is64(const int* ts32, int lane) {
    int probe = ts32[2 * lane + 1];
    return __ballot(probe != 0) == 0ULL;
}

// ---------------------------------------------------------------------------
// Persistent precompute of P (n_nodes x 128, bf16). 512 blocks x 4 waves;
// Bt built once per block, B-fragments hoisted to regs (VGPR=128, no spill
// under lb(256,2) — measured R10), depth-1 A prefetch.
__global__ void __launch_bounds__(256, 2)
precompute_kernel(const float* __restrict__ emb, const float* __restrict__ w1,
                  const float* __restrict__ b1, unsigned short* __restrict__ P,
                  int n_nodes) {
    __shared__ unsigned short bt[16384];   // Bt[c][k] at (c*128+k)^((c&7)<<3)
    const int t    = threadIdx.x;
    const int lane = t & 63;
    const int wid  = t >> 6;
    const int sub  = lane & 15;   // node within tile / D col
    const int g    = lane >> 4;   // k-group / D row group

    // ---- build swizzled Bt from w1 (256x64 f32): thread t owns w1 row t.
    {
        const int k    = t & 127;
        const int half = t >> 7;
        const float4* src = reinterpret_cast<const float4*>(w1 + (size_t)t * 64);
#pragma unroll
        for (int j4 = 0; j4 < 16; ++j4) {
            const float4 v = src[j4];
            const int cb = half * 64 + j4 * 4;
            bt[((cb + 0) * 128 + k) ^ (((cb + 0) & 7) << 3)] = f2bf_rn(v.x);
            bt[((cb + 1) * 128 + k) ^ (((cb + 1) & 7) << 3)] = f2bf_rn(v.y);
            bt[((cb + 2) * 128 + k) ^ (((cb + 2) & 7) << 3)] = f2bf_rn(v.z);
            bt[((cb + 3) * 128 + k) ^ (((cb + 3) & 7) << 3)] = f2bf_rn(v.w);
        }
    }

    // bias regs (cols < 64 only, i.e. nj < 4): cols nj*16 + g*4 .. +3
    float4 bias[4];
#pragma unroll
    for (int nj = 0; nj < 4; ++nj)
        bias[nj] = *reinterpret_cast<const float4*>(b1 + nj * 16 + g * 4);

    __syncthreads();   // Bt ready

    // ---- hoist ALL B-fragments to registers (tile-invariant): 32 x v8s.
    v8s B[4][8];
#pragma unroll
    for (int ks = 0; ks < 4; ++ks)
#pragma unroll
        for (int nj = 0; nj < 8; ++nj) {
            const int c = nj * 16 + sub;
            const int eidx = (c * 128 + ks * 32 + g * 8) ^ ((c & 7) << 3);
            B[ks][nj] = *reinterpret_cast<const v8s*>(&bt[eidx]);
        }

    const int ntiles = (n_nodes + 15) / 16;
    const int gwave  = blockIdx.x * 4 + wid;
    const int nwave  = gridDim.x * 4;

    auto loadA = [&](float4* a, int tt) {
        int row = tt * 16 + sub;
        if (row >= n_nodes) row = n_nodes - 1;
        const float* p = emb + (size_t)row * D_FEAT + g * 8;
#pragma unroll
        for (int ks = 0; ks < 4; ++ks) {
            a[2 * ks]     = *reinterpret_cast<const float4*>(p + ks * 32);
            a[2 * ks + 1] = *reinterpret_cast<const float4*>(p + ks * 32 + 4);
        }
    };

    float4 A0[8], A1[8];
    if (gwave < ntiles) loadA(A0, gwave);

    for (int tt = gwave; tt < ntiles; tt += nwave) {
        const int tn = tt + nwave;
        if (tn < ntiles) loadA(A1, tn);   // prefetch next tile

        f32x4 acc[8];
#pragma unroll
        for (int nj = 0; nj < 8; ++nj) acc[nj] = (f32x4){0.f, 0.f, 0.f, 0.f};

#pragma unroll
        for (int ks = 0; ks < 4; ++ks) {
            const float4 a0 = A0[2 * ks], a1 = A0[2 * ks + 1];
            u32x4 ap;
            ap[0] = pack2(a0.x, a0.y);
            ap[1] = pack2(a0.z, a0.w);
            ap[2] = pack2(a1.x, a1.y);
            ap[3] = pack2(a1.z, a1.w);
            const v8s af = __builtin_bit_cast(v8s, ap);
#pragma unroll
            for (int nj = 0; nj < 8; ++nj)
                // swapped: D[c][node], col=node=sub, row=c_local=g*4+reg
                acc[nj] = __builtin_amdgcn_mfma_f32_16x16x32_bf16(B[ks][nj], af,
                                                                  acc[nj], 0, 0, 0);
        }

        // epilogue: lane holds P cols nj*16+g*4..+3 for node tt*16+sub
        const int node = tt * 16 + sub;
        if (node < n_nodes) {
            unsigned short* prow = P + (size_t)node * 128;
#pragma unroll
            for (int nj = 0; nj < 8; ++nj) {
                float s0 = acc[nj][0], s1 = acc[nj][1];
                float s2 = acc[nj][2], s3 = acc[nj][3];
                if (nj < 4) { s0 += bias[nj].x; s1 += bias[nj].y;
                              s2 += bias[nj].z; s3 += bias[nj].w; }
                uint2 o;
                o.x = pack2(s0, s1);
                o.y = pack2(s2, s3);
                *reinterpret_cast<uint2*>(prow + nj * 16 + g * 4) = o;
            }
        }

#pragma unroll
        for (int i = 0; i < 8; ++i) A0[i] = A1[i];
    }
}

// ---------------------------------------------------------------------------
// Edge pass: 8 lanes per edge, 8 edges per wave. 16B uint4 loads per half,
// bf16 unpack via bit ops, 3-step shuffle reduce. (measured ~9.3 us warm)
__device__ inline float pairterm(unsigned aw, unsigned bw, float w0, float w1) {
    float a0 = __builtin_bit_cast(float, aw << 16);
    float a1 = __builtin_bit_cast(float, aw & 0xFFFF0000u);
    float b0 = __builtin_bit_cast(float, bw << 16);
    float b1 = __builtin_bit_cast(float, bw & 0xFFFF0000u);
    float h0 = a0 + b0; h0 = h0 > 0.f ? h0 : 0.f;
    float h1 = a1 + b1; h1 = h1 > 0.f ? h1 : 0.f;
    return h0 * w0 + h1 * w1;
}

__global__ void __launch_bounds__(256)
edge_kernel(const unsigned short* __restrict__ P, const void* __restrict__ ts,
            const float* __restrict__ w2, float* __restrict__ out, int n_edges) {
    const int lane = threadIdx.x & 63;
    const int wid  = threadIdx.x >> 6;
    const int sub  = lane & 7;   // 8 lanes per edge
    const int grp  = lane >> 3;  // 8 edges per wave
    const int gw   = blockIdx.x * 4 + wid;
    const int nw   = gridDim.x * 4;

    const int* ts32 = (const int*)ts;
    const long long* ts64 = (const long long*)ts;
    const bool is64 = detect_is64(ts32, lane);

    const float4 w2a = *reinterpret_cast<const float4*>(w2 + sub * 8);
    const float4 w2b = *reinterpret_cast<const float4*>(w2 + sub * 8 + 4);

    for (int e = gw * 8 + grp; e < n_edges; e += nw * 8) {
        long long s, d;
        if (is64) { s = ts64[2 * e]; d = ts64[2 * e + 1]; }
        else      { s = ts32[2 * e]; d = ts32[2 * e + 1]; }
        const uint4 a = *reinterpret_cast<const uint4*>(P + (size_t)s * 128 + sub * 8);
        const uint4 b = *reinterpret_cast<const uint4*>(P + (size_t)d * 128 + 64 + sub * 8);
        float v = pairterm(a.x, b.x, w2a.x, w2a.y)
                + pairterm(a.y, b.y, w2a.z, w2a.w)
                + pairterm(a.z, b.z, w2b.x, w2b.y)
                + pairterm(a.w, b.w, w2b.z, w2b.w);
#pragma unroll
        for (int off = 1; off < 8; off <<= 1) v += __shfl_xor(v, off);
        if (sub == 0) out[e] = v;
    }
}

// ---------------------------------------------------------------------------
// Fallback (ws too small for P): fused gather + f32 MLP, wave per edge.
__global__ void __launch_bounds__(256)
direct_kernel(const float* __restrict__ emb, const void* __restrict__ ts,
              const float* __restrict__ w1, const float* __restrict__ b1,
              const float* __restrict__ w2, float* __restrict__ out, int n_edges) {
    const int lane = threadIdx.x & 63;
    const int gw   = blockIdx.x * (blockDim.x >> 6) + (threadIdx.x >> 6);
    const int nw   = gridDim.x * (blockDim.x >> 6);
    const float w2v  = w2[lane];
    const float bias = b1[lane];
    const int* ts32 = (const int*)ts;
    const long long* ts64 = (const long long*)ts;
    const bool is64 = detect_is64(ts32, lane);

    for (int e = gw; e < n_edges; e += nw) {
        long long s, d;
        if (is64) { s = ts64[2 * e]; d = ts64[2 * e + 1]; }
        else      { s = ts32[2 * e]; d = ts32[2 * e + 1]; }
        const float4* s4 = reinterpret_cast<const float4*>(emb + s * D_FEAT);
        const float4* d4 = reinterpret_cast<const float4*>(emb + d * D_FEAT);
        float acc = bias;
#pragma unroll
        for (int k4 = 0; k4 < 32; ++k4) {
            float4 r = s4[k4];
            acc += r.x * w1[(4 * k4 + 0) * 64 + lane];
            acc += r.y * w1[(4 * k4 + 1) * 64 + lane];
            acc += r.z * w1[(4 * k4 + 2) * 64 + lane];
            acc += r.w * w1[(4 * k4 + 3) * 64 + lane];
        }
#pragma unroll
        for (int k4 = 0; k4 < 32; ++k4) {
            float4 r = d4[k4];
            acc += r.x * w1[(128 + 4 * k4 + 0) * 64 + lane];
            acc += r.y * w1[(128 + 4 * k4 + 1) * 64 + lane];
            acc += r.z * w1[(128 + 4 * k4 + 2) * 64 + lane];
            acc += r.w * w1[(128 + 4 * k4 + 3) * 64 + lane];
        }
        float h = acc > 0.0f ? acc : 0.0f;
        float v = h * w2v;
#pragma unroll
        for (int off = 32; off > 0; off >>= 1) v += __shfl_xor(v, off);
        if (lane == 0) out[e] = v;
    }
}

// ---------------------------------------------------------------------------
extern "C" void kernel_launch(void* const* d_in, const int* in_sizes, int n_in,
                              void* d_out, int out_size, void* d_ws, size_t ws_size,
                              hipStream_t stream) {
    const float* emb = (const float*)d_in[0];
    const void*  ts  = d_in[1];
    const float* w1  = (const float*)d_in[2];
    const float* b1  = (const float*)d_in[3];
    const float* w2  = (const float*)d_in[4];
    float* out = (float*)d_out;

    const int n_nodes = in_sizes[0] / D_FEAT;   // 100000
    const int n_edges = in_sizes[1] / 2;        // 300000

    const size_t p_bytes = (size_t)n_nodes * 128 * sizeof(unsigned short);

    if (ws_size >= p_bytes) {
        unsigned short* P = (unsigned short*)d_ws;
        // 512 blocks = best measured config (R9: 37.5 us).
        precompute_kernel<<<512, 256, 0, stream>>>(emb, w1, b1, P, n_nodes);
        edge_kernel<<<2048, 256, 0, stream>>>(P, ts, w2, out, n_edges);
    } else {
        direct_kernel<<<2048, 256, 0, stream>>>(emb, ts, w1, b1, w2, out, n_edges);
    }
}